// Round 10
// baseline (134.156 us; speedup 1.0000x reference)
//
#include <hip/hip_runtime.h>
#include <cstdint>

#define CN (384*1024)          // 393216
#define BCN (16*CN)            // 6291456
#define EPS 1e-5f

typedef float f32x2 __attribute__((ext_vector_type(2)));

// workspace layout (bytes)
#define WPT_OFF   0u           // f32[384][384] = 589824
#define WQB_OFF   589824u      // bf16-as-u16[385][384] (row 384 = zeros), ends 885504
#define QINV_OFF  1179648u
#define QOFF_OFF  (QINV_OFF + 1536u)
#define PINV_OFF  (QINV_OFF + 3072u)
#define POFF_OFF  (QINV_OFF + 4608u)
#define C0_OFF    (QINV_OFF + 6144u)
#define LCNT2_OFF 1187840u     // u8[1024 blocks][64 units], ends 1253376
#define XM_OFF    1310720u     // u64[4][16][16][384] n-packed spikes, ends 4456448
#define XMT_OFF   4456448u     // u64[4][16][1024][6] c-packed spikes, ends 7602176
#define LISTS2_OFF 7602176u    // u16[1024][64][24] offsets (idx*3), ends ~10748032
#define MST_OFF   XM_OFF       // masked q-spikes; reuses xm (dead after k1b)

// ---------------- K0a: transposes: wp -> f32 wpT, wq -> bf16 wqb (+ zero row) ------
__global__ __launch_bounds__(256) void k0_transpose(const float* __restrict__ wq,
                                                    const float* __restrict__ wp,
                                                    char* __restrict__ ws) {
    int bid = blockIdx.x;
    if (bid < 576) {
        int i = bid * 256 + threadIdx.x;             // 0..147455
        int c = i / 384, o = i % 384;
        ((float*)(ws + WPT_OFF))[c * 384 + o] = wp[o * 384 + c];
    } else {
        int j = (bid - 576) * 256 + threadIdx.x;     // 0..147967
        if (j >= 147840) return;                     // 385*384
        int r = j / 384, o = j % 384;
        unsigned short v = 0;
        if (r < 384) {
            unsigned u = __float_as_uint(wq[o * 384 + r]);
            v = (unsigned short)((u + 0x7fffu + ((u >> 16) & 1u)) >> 16);  // rne bf16
        }
        ((unsigned short*)(ws + WQB_OFF))[j] = v;
    }
}

// ---------------- K0b: BN constants ----------------
__global__ void k0_consts(const float* __restrict__ qg, const float* __restrict__ qb,
                          const float* __restrict__ qm, const float* __restrict__ qv,
                          const float* __restrict__ pg, const float* __restrict__ pb,
                          const float* __restrict__ pm, const float* __restrict__ pv,
                          const float* __restrict__ bp, char* __restrict__ ws) {
    int i = threadIdx.x;                         // 384 threads
    float qi = qg[i] / sqrtf(qv[i] + EPS);
    ((float*)(ws + QINV_OFF))[i] = qi;
    ((float*)(ws + QOFF_OFF))[i] = qb[i] - qm[i] * qi;
    float pi = pg[i] / sqrtf(pv[i] + EPS);
    float po = pb[i] - pm[i] * pi;
    ((float*)(ws + PINV_OFF))[i] = pi;
    ((float*)(ws + POFF_OFF))[i] = po;
    ((float*)(ws + C0_OFF))[i] = bp[i] * pi + po;   // output value when GEMM2 input is all-zero
}

// ---------------- K1: shortcut LIF -> n-packed spike bitmasks ----------------
__global__ __launch_bounds__(256) void k1_lif(const float* __restrict__ x,
                                              unsigned long long* __restrict__ xm) {
    int wid  = (blockIdx.x * 256 + threadIdx.x) >> 6;   // 0..98303
    int lane = threadIdx.x & 63;
    int c = wid % 384;
    int g = (wid / 384) & 15;
    int b = wid / (384 * 16);
    const float* xp = x + (size_t)b * CN + (size_t)c * 1024 + g * 64 + lane;
    float v = 0.f;
    #pragma unroll
    for (int t = 0; t < 4; ++t) {
        float xv = xp[(size_t)t * BCN];
        float h = v + (xv - v) * 0.5f;                  // v + (x - v)/tau, tau = 2
        bool s = (h >= 1.0f);
        unsigned long long m = __ballot(s);
        v = s ? 0.f : h;
        if (lane == 0) xm[(((size_t)t * 16 + b) * 16 + g) * 384 + c] = m;
    }
}

// ---------------- K1b: 64x64 bit transpose: n-packed -> c-packed ----------------
__global__ __launch_bounds__(256) void k1b_transpose(const unsigned long long* __restrict__ xm,
                                                     unsigned long long* __restrict__ xmT) {
    int wid  = (blockIdx.x * 256 + threadIdx.x) >> 6;   // 0..6143
    int lane = threadIdx.x & 63;
    int cg = wid % 6;
    int g  = (wid / 6) % 16;
    int tb = wid / 96;                                  // t*16 + b
    unsigned long long W = xm[((size_t)tb * 16 + g) * 384 + cg * 64 + lane];
    unsigned long long T = 0ull;
    #pragma unroll
    for (int k = 0; k < 64; ++k) {
        unsigned long long bk = __ballot((W >> k) & 1ull);  // bit c = spike(c, n=g*64+k)
        if (lane == k) T = bk;
    }
    xmT[((size_t)tb * 1024 + g * 64 + lane) * 6 + cg] = T;
}

// ---------------- K1c: c-packed bitmasks -> per-block u16 offset lists -------------
// Column (t,b,n) -> block (b*64 + n>>4), unit (n&15)*4 + t. Entry = row_idx*3
// (<<8 gives the 768B-row byte offset). ALL 24 slots always written (pad = 1152,
// the zero row) so k2's hot path is branchless. k>24: lcnt=0xFF -> bitmask fallback.
__global__ __launch_bounds__(256) void k1c_lists(const unsigned long long* __restrict__ xmT,
                                                 unsigned short* __restrict__ lists2,
                                                 unsigned char* __restrict__ lcnt2) {
    int col = blockIdx.x * 256 + threadIdx.x;           // 0..65535 = ((t*16+b)<<10)+n
    int t = col >> 14, b = (col >> 10) & 15, n = col & 1023;
    int blockid = b * 64 + (n >> 4);
    int un = (n & 15) * 4 + t;
    const unsigned long long* mp = xmT + (size_t)col * 6;
    unsigned short* lp = lists2 + ((size_t)blockid * 64 + un) * 24;
    int k = 0;
    #pragma unroll
    for (int cg = 0; cg < 6; ++cg) {
        unsigned long long m = mp[cg];
        while (m) {
            int j = __builtin_ctzll(m);
            m &= m - 1;
            if (k < 24) lp[k] = (unsigned short)((cg * 64 + j) * 3);
            ++k;
        }
    }
    int kk = k > 24 ? 24 : k;
    for (int i = kk; i < 24; ++i) lp[i] = 1152;         // 384*3 -> zero row (always pad)
    lcnt2[(size_t)blockid * 64 + un] =
        (k > 24) ? 0xFF : (unsigned char)((k + 7) >> 3);
}

// ---------------- K2: asm-saddr gather GEMM1 + BN + q-LIF + attn mask --------------
// block = (b, nt16); 384 threads = 2 n-streams x 192; thread owns o-pair (2pj,2pj+1)
// read as one u32. Metadata VGPR-lane-cached; v_readlane -> SGPR offsets; row bases
// built in SALU; loads are EXPLICIT saddr-form inline asm (0 address VALU / load).
// Per nlo: 64 volatile asm loads in flight -> one vmcnt(0) drain -> unpack.
#define BLO(w) __uint_as_float((w) << 16)
#define BHI(w) __uint_as_float((w) & 0xFFFF0000u)
#define PK(w)  ((f32x2){BLO(w), BHI(w)})

// two saddr loads from one packed u16-offset word (uniform W)
#define LDPAIR(D0, D1, W) do {                                                    \
    unsigned long long b0_ = (unsigned long long)(uintptr_t)wqc                   \
                             + ((unsigned long long)((W) & 0xffffu) << 8);        \
    unsigned long long b1_ = (unsigned long long)(uintptr_t)wqc                   \
                             + ((unsigned long long)((W) >> 16) << 8);            \
    asm volatile("global_load_dword %0, %1, %2" : "=v"(D0) : "v"(voff), "s"(b0_));\
    asm volatile("global_load_dword %0, %1, %2" : "=v"(D1) : "v"(voff), "s"(b1_));\
} while (0)

// compiler-path gather (rare phases only)
#define G8C(C0, C1, C2, C3) do {                                                  \
    const unsigned W0_ = (unsigned)__builtin_amdgcn_readlane((int)(C0), un);      \
    const unsigned W1_ = (unsigned)__builtin_amdgcn_readlane((int)(C1), un);      \
    const unsigned W2_ = (unsigned)__builtin_amdgcn_readlane((int)(C2), un);      \
    const unsigned W3_ = (unsigned)__builtin_amdgcn_readlane((int)(C3), un);      \
    const unsigned d0_ = *(const unsigned*)(wqc + ((size_t)(W0_ & 0xffffu) << 8) + voff); \
    const unsigned d1_ = *(const unsigned*)(wqc + ((size_t)(W0_ >> 16) << 8) + voff);     \
    const unsigned d2_ = *(const unsigned*)(wqc + ((size_t)(W1_ & 0xffffu) << 8) + voff); \
    const unsigned d3_ = *(const unsigned*)(wqc + ((size_t)(W1_ >> 16) << 8) + voff);     \
    const unsigned d4_ = *(const unsigned*)(wqc + ((size_t)(W2_ & 0xffffu) << 8) + voff); \
    const unsigned d5_ = *(const unsigned*)(wqc + ((size_t)(W2_ >> 16) << 8) + voff);     \
    const unsigned d6_ = *(const unsigned*)(wqc + ((size_t)(W3_ & 0xffffu) << 8) + voff); \
    const unsigned d7_ = *(const unsigned*)(wqc + ((size_t)(W3_ >> 16) << 8) + voff);     \
    A2 += ((PK(d0_) + PK(d1_)) + (PK(d2_) + PK(d3_)))                             \
        + ((PK(d4_) + PK(d5_)) + (PK(d6_) + PK(d7_)));                            \
} while (0)

__global__ __launch_bounds__(384, 4) void k2_qpath(const char* __restrict__ wqc,
                                                   const float* __restrict__ qinv_,
                                                   const float* __restrict__ qoff_,
                                                   const unsigned short* __restrict__ lists2,
                                                   const unsigned char* __restrict__ lcnt2,
                                                   const unsigned long long* __restrict__ xmT,
                                                   const unsigned char* __restrict__ ak,
                                                   const unsigned char* __restrict__ av,
                                                   unsigned long long* __restrict__ msT) {
    const int tid  = threadIdx.x;
    const int s    = tid / 192;                  // n-stream (waves 0-2 / 3-5)
    const int pj   = tid - s * 192;              // o-pair index 0..191
    const int lane = tid & 63;
    const int wv_  = (tid >> 6) % 3;             // wave within stream -> o-base 128*wv_
    const int nt   = blockIdx.x & 63;
    const int b    = blockIdx.x >> 6;
    const int voff = pj * 4;
    const float2 qi2 = ((const float2*)qinv_)[pj];
    const float2 qo2 = ((const float2*)qoff_)[pj];

    // lane-cache the block's gather metadata: lane u holds unit u's 24 u16 offsets
    const char* lb = (const char*)lists2 + (size_t)blockIdx.x * 3072 + lane * 48;
    const uint4 L0 = *(const uint4*)lb;           // slots 0-7
    const uint4 L1 = *(const uint4*)(lb + 16);    // slots 8-15
    const uint4 L2 = *(const uint4*)(lb + 32);    // slots 16-23
    const unsigned lcv = *(const unsigned*)((const char*)lcnt2
                          + (size_t)blockIdx.x * 64 + (lane & 15) * 4);

    for (int nlo = 0; nlo < 8; ++nlo) {
        const int n = nt * 16 + s * 8 + nlo;
        const unsigned lcw = (unsigned)__builtin_amdgcn_readlane((int)lcv, s * 8 + nlo);
        unsigned dr[4][16];
        // ---- issue all 64 saddr loads (volatile asm, stay in flight) ----
        #pragma unroll
        for (int t = 0; t < 4; ++t) {
            const int un = (s * 8 + nlo) * 4 + t;           // wave-uniform
            const unsigned Wa = (unsigned)__builtin_amdgcn_readlane((int)L0.x, un);
            const unsigned Wb = (unsigned)__builtin_amdgcn_readlane((int)L0.y, un);
            const unsigned Wc = (unsigned)__builtin_amdgcn_readlane((int)L0.z, un);
            const unsigned Wd = (unsigned)__builtin_amdgcn_readlane((int)L0.w, un);
            const unsigned We = (unsigned)__builtin_amdgcn_readlane((int)L1.x, un);
            const unsigned Wf = (unsigned)__builtin_amdgcn_readlane((int)L1.y, un);
            const unsigned Wg = (unsigned)__builtin_amdgcn_readlane((int)L1.z, un);
            const unsigned Wh = (unsigned)__builtin_amdgcn_readlane((int)L1.w, un);
            LDPAIR(dr[t][0],  dr[t][1],  Wa);
            LDPAIR(dr[t][2],  dr[t][3],  Wb);
            LDPAIR(dr[t][4],  dr[t][5],  Wc);
            LDPAIR(dr[t][6],  dr[t][7],  Wd);
            LDPAIR(dr[t][8],  dr[t][9],  We);
            LDPAIR(dr[t][10], dr[t][11], Wf);
            LDPAIR(dr[t][12], dr[t][13], Wg);
            LDPAIR(dr[t][14], dr[t][15], Wh);
        }
        asm volatile("s_waitcnt vmcnt(0)");      // drain the 64 asm loads
        __builtin_amdgcn_sched_barrier(0);       // rule #18: consumers stay below
        // ---- unpack + accumulate ----
        f32x2 acc2[4];
        #pragma unroll
        for (int t = 0; t < 4; ++t) {
            f32x2 u0 = (PK(dr[t][0])  + PK(dr[t][1]))  + (PK(dr[t][2])  + PK(dr[t][3]));
            f32x2 u1 = (PK(dr[t][4])  + PK(dr[t][5]))  + (PK(dr[t][6])  + PK(dr[t][7]));
            f32x2 u2 = (PK(dr[t][8])  + PK(dr[t][9]))  + (PK(dr[t][10]) + PK(dr[t][11]));
            f32x2 u3 = (PK(dr[t][12]) + PK(dr[t][13])) + (PK(dr[t][14]) + PK(dr[t][15]));
            acc2[t] = (u0 + u1) + (u2 + u3);
        }
        // ---- rare third round (k = 17..24), scalar-uniform branch ----
        #pragma unroll
        for (int t = 0; t < 4; ++t) {
            if (((lcw >> (8 * t)) & 0xffu) == 3u) {
                const int un = (s * 8 + nlo) * 4 + t;
                f32x2 A2 = acc2[t];
                G8C(L2.x, L2.y, L2.z, L2.w);
                acc2[t] = A2;
            }
        }
        // ---- overflow fallback (k > 24, ~never), recompute from zero ----
        #pragma unroll
        for (int t = 0; t < 4; ++t) {
            if (((lcw >> (8 * t)) & 0xffu) == 0xffu) {
                const int col = ((t * 16 + b) << 10) + n;
                const unsigned long long* mp = xmT + (size_t)col * 6;
                f32x2 A2 = {0.f, 0.f};
                #pragma unroll
                for (int cg = 0; cg < 6; ++cg) {
                    unsigned long long mm = mp[cg];
                    while (mm) {
                        int j = __builtin_ctzll(mm);
                        mm &= mm - 1;
                        unsigned ww = *(const unsigned*)(wqc + (cg * 64 + j) * 768 + voff);
                        A2 += PK(ww);
                    }
                }
                acc2[t] = A2;
            }
        }
        // ---- BN + LIF + attn-mask epilogue for the two owned o's ----
        float vL = 0.f, vH = 0.f;
        #pragma unroll
        for (int t = 0; t < 4; ++t) {
            const int col = ((t * 16 + b) << 10) + n;
            float qL = acc2[t].x * qi2.x + qo2.x;
            float qH = acc2[t].y * qi2.y + qo2.y;
            float hL = 0.5f * (vL + qL);
            float hH = 0.5f * (vH + qH);
            bool sL = (hL >= 1.0f), sH = (hH >= 1.0f);
            vL = sL ? 0.f : hL;  vH = sH ? 0.f : hH;
            if (sL) {   // rare: attn-mask lookup only on q-spike
                size_t ix = ((size_t)((t * 16 + b) * 384 + 2 * pj) << 10) + n;
                sL = (ak[ix] != 0) && (av[ix] != 0);
            }
            if (sH) {
                size_t ix = ((size_t)((t * 16 + b) * 384 + 2 * pj + 1) << 10) + n;
                sH = (ak[ix] != 0) && (av[ix] != 0);
            }
            unsigned long long bL = __ballot(sL);
            unsigned long long bH = __ballot(sH);
            // word u=2*wv_+h: bit l -> o = 128*wv_ + 2*l + h
            if (lane == 0) {
                msT[(size_t)col * 6 + 2 * wv_]     = bL;
                msT[(size_t)col * 6 + 2 * wv_ + 1] = bH;
            }
        }
    }
}

// ---------------- K3: proj GEMM2 + bias + BN (gather-based, atomic-free) ----------
__global__ __launch_bounds__(384) void k3_proj(const float* __restrict__ wpT,
                                               const float* __restrict__ pinv_,
                                               const float* __restrict__ poff_,
                                               const float* __restrict__ bp,
                                               const float* __restrict__ c0,
                                               const unsigned long long* __restrict__ msT,
                                               float* __restrict__ out) {
    __shared__ unsigned int wflag[6];
    const int tid = threadIdx.x;
    const int bid = blockIdx.x;
    const int g = bid & 15, b = (bid >> 4) & 15, t = bid >> 8;
    const unsigned long long* mbase = msT + ((size_t)(t * 16 + b) * 1024 + g * 64) * 6;
    unsigned long long m = mbase[tid];           // 384 words: n-local = tid/6, u = tid%6
    unsigned long long anyb = __ballot(m != 0ull);
    if ((tid & 63) == 0) wflag[tid >> 6] = (anyb != 0ull) ? 1u : 0u;
    __syncthreads();
    unsigned int any = wflag[0] | wflag[1] | wflag[2] | wflag[3] | wflag[4] | wflag[5];
    size_t obase = (size_t)(t * 16 + b) * 384;

    if (!any) {
        // all-zero GEMM2 input: out = bp*inv + off, coalesced float4 stores
        #pragma unroll
        for (int k = 0; k < 16; ++k) {
            int i = tid + k * 384;               // 6144 float4 units in the (384o x 64n) tile
            int o = i >> 4, n4 = i & 15;
            float vv = c0[o];
            float4* dst = (float4*)out + (obase + o) * 256 + g * 16 + n4;
            *dst = make_float4(vv, vv, vv, vv);
        }
        return;
    }
    // slow path (never taken on this input): per-n VGPR gather.
    // word u: bit l -> input channel 128*(u>>1) + 2*l + (u&1)   [matches k2's layout]
    float pi = pinv_[tid], po = poff_[tid], bb = bp[tid];
    for (int nl = 0; nl < 64; ++nl) {
        float acc = 0.f;
        #pragma unroll
        for (int u = 0; u < 6; ++u) {
            unsigned long long mm = mbase[nl * 6 + u];
            while (mm) {
                int j = __builtin_ctzll(mm);
                mm &= mm - 1;
                int row = 128 * (u >> 1) + 2 * j + (u & 1);
                acc += wpT[(size_t)row * 384 + tid];
            }
        }
        out[(obase + tid) * 1024 + g * 64 + nl] = (acc + bb) * pi + po;
    }
}

extern "C" void kernel_launch(void* const* d_in, const int* in_sizes, int n_in,
                              void* d_out, int out_size, void* d_ws, size_t ws_size,
                              hipStream_t stream) {
    const float* x  = (const float*)d_in[0];
    const unsigned char* ak = (const unsigned char*)d_in[1];
    const unsigned char* av = (const unsigned char*)d_in[2];
    const float* wq = (const float*)d_in[3];
    const float* qg = (const float*)d_in[4];
    const float* qb = (const float*)d_in[5];
    const float* qm = (const float*)d_in[6];
    const float* qv = (const float*)d_in[7];
    const float* wp = (const float*)d_in[8];
    const float* bp = (const float*)d_in[9];
    const float* pg = (const float*)d_in[10];
    const float* pb = (const float*)d_in[11];
    const float* pm = (const float*)d_in[12];
    const float* pv = (const float*)d_in[13];
    char* ws = (char*)d_ws;
    float* out = (float*)d_out;

    hipLaunchKernelGGL(k0_transpose, dim3(1154), dim3(256), 0, stream, wq, wp, ws);
    hipLaunchKernelGGL(k0_consts, dim3(1), dim3(384), 0, stream,
                       qg, qb, qm, qv, pg, pb, pm, pv, bp, ws);
    hipLaunchKernelGGL(k1_lif, dim3(24576), dim3(256), 0, stream,
                       x, (unsigned long long*)(ws + XM_OFF));
    hipLaunchKernelGGL(k1b_transpose, dim3(1536), dim3(256), 0, stream,
                       (const unsigned long long*)(ws + XM_OFF),
                       (unsigned long long*)(ws + XMT_OFF));
    hipLaunchKernelGGL(k1c_lists, dim3(256), dim3(256), 0, stream,
                       (const unsigned long long*)(ws + XMT_OFF),
                       (unsigned short*)(ws + LISTS2_OFF),
                       (unsigned char*)(ws + LCNT2_OFF));
    hipLaunchKernelGGL(k2_qpath, dim3(1024), dim3(384), 0, stream,
                       (const char*)(ws + WQB_OFF),
                       (const float*)(ws + QINV_OFF), (const float*)(ws + QOFF_OFF),
                       (const unsigned short*)(ws + LISTS2_OFF),
                       (const unsigned char*)(ws + LCNT2_OFF),
                       (const unsigned long long*)(ws + XMT_OFF), ak, av,
                       (unsigned long long*)(ws + MST_OFF));
    hipLaunchKernelGGL(k3_proj, dim3(1024), dim3(384), 0, stream,
                       (const float*)(ws + WPT_OFF), (const float*)(ws + PINV_OFF),
                       (const float*)(ws + POFF_OFF), bp, (const float*)(ws + C0_OFF),
                       (const unsigned long long*)(ws + MST_OFF), out);
}

// Round 11
// 111.334 us; speedup vs baseline: 1.2050x; 1.2050x over previous
//
#include <hip/hip_runtime.h>
#include <cstdint>

#define CN (384*1024)          // 393216
#define BCN (16*CN)            // 6291456
#define EPS 1e-5f

typedef float f32x2 __attribute__((ext_vector_type(2)));

// workspace layout (bytes)
#define WPT_OFF   0u           // f32[384][384] = 589824
#define WQB_OFF   589824u      // bf16-as-u16[385][384] (row 384 = zeros), ends 885504
#define QINV_OFF  1179648u
#define QOFF_OFF  (QINV_OFF + 1536u)
#define PINV_OFF  (QINV_OFF + 3072u)
#define POFF_OFF  (QINV_OFF + 4608u)
#define C0_OFF    (QINV_OFF + 6144u)
#define LCNT2_OFF 1187840u     // u8[1024 blocks][64 units], ends 1253376
#define XM_OFF    1310720u     // u64[4][16][16][384] n-packed spikes, ends 4456448
#define XMT_OFF   4456448u     // u64[4][16][1024][6] c-packed spikes, ends 7602176
#define LISTS2_OFF 7602176u    // u16[1024][64][24] offsets (idx*3), ends ~10748032
#define MST_OFF   XM_OFF       // masked q-spikes u64[col][6]; reuses xm (dead after k1b)

// ---------------- K0a: transposes: wp -> f32 wpT, wq -> bf16 wqb (+ zero row) ------
__global__ __launch_bounds__(256) void k0_transpose(const float* __restrict__ wq,
                                                    const float* __restrict__ wp,
                                                    char* __restrict__ ws) {
    int bid = blockIdx.x;
    if (bid < 576) {
        int i = bid * 256 + threadIdx.x;             // 0..147455
        int c = i / 384, o = i % 384;
        ((float*)(ws + WPT_OFF))[c * 384 + o] = wp[o * 384 + c];
    } else {
        int j = (bid - 576) * 256 + threadIdx.x;     // 0..147967
        if (j >= 147840) return;                     // 385*384
        int r = j / 384, o = j % 384;
        unsigned short v = 0;
        if (r < 384) {
            unsigned u = __float_as_uint(wq[o * 384 + r]);
            v = (unsigned short)((u + 0x7fffu + ((u >> 16) & 1u)) >> 16);  // rne bf16
        }
        ((unsigned short*)(ws + WQB_OFF))[j] = v;
    }
}

// ---------------- K0b: BN constants ----------------
__global__ void k0_consts(const float* __restrict__ qg, const float* __restrict__ qb,
                          const float* __restrict__ qm, const float* __restrict__ qv,
                          const float* __restrict__ pg, const float* __restrict__ pb,
                          const float* __restrict__ pm, const float* __restrict__ pv,
                          const float* __restrict__ bp, char* __restrict__ ws) {
    int i = threadIdx.x;                         // 384 threads
    float qi = qg[i] / sqrtf(qv[i] + EPS);
    ((float*)(ws + QINV_OFF))[i] = qi;
    ((float*)(ws + QOFF_OFF))[i] = qb[i] - qm[i] * qi;
    float pi = pg[i] / sqrtf(pv[i] + EPS);
    float po = pb[i] - pm[i] * pi;
    ((float*)(ws + PINV_OFF))[i] = pi;
    ((float*)(ws + POFF_OFF))[i] = po;
    ((float*)(ws + C0_OFF))[i] = bp[i] * pi + po;   // output value when GEMM2 input is all-zero
}

// ---------------- K1: shortcut LIF -> n-packed spike bitmasks ----------------
__global__ __launch_bounds__(256) void k1_lif(const float* __restrict__ x,
                                              unsigned long long* __restrict__ xm) {
    int wid  = (blockIdx.x * 256 + threadIdx.x) >> 6;   // 0..98303
    int lane = threadIdx.x & 63;
    int c = wid % 384;
    int g = (wid / 384) & 15;
    int b = wid / (384 * 16);
    const float* xp = x + (size_t)b * CN + (size_t)c * 1024 + g * 64 + lane;
    float v = 0.f;
    #pragma unroll
    for (int t = 0; t < 4; ++t) {
        float xv = xp[(size_t)t * BCN];
        float h = v + (xv - v) * 0.5f;                  // v + (x - v)/tau, tau = 2
        bool s = (h >= 1.0f);
        unsigned long long m = __ballot(s);
        v = s ? 0.f : h;
        if (lane == 0) xm[(((size_t)t * 16 + b) * 16 + g) * 384 + c] = m;
    }
}

// ---------------- K1b: 64x64 bit transpose: n-packed -> c-packed ----------------
__global__ __launch_bounds__(256) void k1b_transpose(const unsigned long long* __restrict__ xm,
                                                     unsigned long long* __restrict__ xmT) {
    int wid  = (blockIdx.x * 256 + threadIdx.x) >> 6;   // 0..6143
    int lane = threadIdx.x & 63;
    int cg = wid % 6;
    int g  = (wid / 6) % 16;
    int tb = wid / 96;                                  // t*16 + b
    unsigned long long W = xm[((size_t)tb * 16 + g) * 384 + cg * 64 + lane];
    unsigned long long T = 0ull;
    #pragma unroll
    for (int k = 0; k < 64; ++k) {
        unsigned long long bk = __ballot((W >> k) & 1ull);  // bit c = spike(c, n=g*64+k)
        if (lane == k) T = bk;
    }
    xmT[((size_t)tb * 1024 + g * 64 + lane) * 6 + cg] = T;
}

// ---------------- K1c: c-packed bitmasks -> per-block u16 offset lists -------------
// Column (t,b,n) -> block (b*64 + n>>4), unit (n&15)*4 + t. Entry = row_idx*3
// (<<8 gives the 768B-row byte offset). ALL 24 slots always written (pad = 1152,
// the zero row). lcnt = ceil(k/8) (0..3) or 0xFF (k>24 -> bitmask fallback).
__global__ __launch_bounds__(256) void k1c_lists(const unsigned long long* __restrict__ xmT,
                                                 unsigned short* __restrict__ lists2,
                                                 unsigned char* __restrict__ lcnt2) {
    int col = blockIdx.x * 256 + threadIdx.x;           // 0..65535 = ((t*16+b)<<10)+n
    int t = col >> 14, b = (col >> 10) & 15, n = col & 1023;
    int blockid = b * 64 + (n >> 4);
    int un = (n & 15) * 4 + t;
    const unsigned long long* mp = xmT + (size_t)col * 6;
    unsigned short* lp = lists2 + ((size_t)blockid * 64 + un) * 24;
    int k = 0;
    #pragma unroll
    for (int cg = 0; cg < 6; ++cg) {
        unsigned long long m = mp[cg];
        while (m) {
            int j = __builtin_ctzll(m);
            m &= m - 1;
            if (k < 24) lp[k] = (unsigned short)((cg * 64 + j) * 3);
            ++k;
        }
    }
    int kk = k > 24 ? 24 : k;
    for (int i = kk; i < 24; ++i) lp[i] = 1152;         // 384*3 -> zero row (always pad)
    lcnt2[(size_t)blockid * 64 + un] =
        (k > 24) ? 0xFF : (unsigned char)((k + 7) >> 3);
}

// ---------------- K2: wave-per-row dwordx3 gather GEMM1 + BN + q-LIF + mask --------
// block = (b, nt16), 512 threads = 8 waves; wave w owns n-locals {2w, 2w+1} (full
// LIF t-chain in-register). One wave loads a whole 768B row per dwordx3 (lane owns
// o = lane*6+e, e<6). Unit index is wave-uniform -> readlane metadata -> row bases.
#define BLO(w) __uint_as_float((w) << 16)
#define BHI(w) __uint_as_float((w) & 0xFFFF0000u)
#define PK(w)  ((f32x2){BLO(w), BHI(w)})
#define RL(v, l) ((unsigned)__builtin_amdgcn_readlane((int)(v), (l)))

// 8 row-loads (one per slot) from 4 packed u16-offset words, accumulate 6 lanes-o
#define GROW8(W0, W1, W2, W3) do {                                                \
    uint3 d0_ = *(const uint3*)(wqc + ((size_t)((W0) & 0xffffu) << 8) + voff);    \
    uint3 d1_ = *(const uint3*)(wqc + ((size_t)((W0) >> 16) << 8) + voff);        \
    uint3 d2_ = *(const uint3*)(wqc + ((size_t)((W1) & 0xffffu) << 8) + voff);    \
    uint3 d3_ = *(const uint3*)(wqc + ((size_t)((W1) >> 16) << 8) + voff);        \
    uint3 d4_ = *(const uint3*)(wqc + ((size_t)((W2) & 0xffffu) << 8) + voff);    \
    uint3 d5_ = *(const uint3*)(wqc + ((size_t)((W2) >> 16) << 8) + voff);        \
    uint3 d6_ = *(const uint3*)(wqc + ((size_t)((W3) & 0xffffu) << 8) + voff);    \
    uint3 d7_ = *(const uint3*)(wqc + ((size_t)((W3) >> 16) << 8) + voff);        \
    s0 += ((PK(d0_.x) + PK(d1_.x)) + (PK(d2_.x) + PK(d3_.x)))                     \
        + ((PK(d4_.x) + PK(d5_.x)) + (PK(d6_.x) + PK(d7_.x)));                    \
    s1 += ((PK(d0_.y) + PK(d1_.y)) + (PK(d2_.y) + PK(d3_.y)))                     \
        + ((PK(d4_.y) + PK(d5_.y)) + (PK(d6_.y) + PK(d7_.y)));                    \
    s2 += ((PK(d0_.z) + PK(d1_.z)) + (PK(d2_.z) + PK(d3_.z)))                     \
        + ((PK(d4_.z) + PK(d5_.z)) + (PK(d6_.z) + PK(d7_.z)));                    \
} while (0)

__global__ __launch_bounds__(512, 2) void k2_qpath(const char* __restrict__ wqc,
                                                   const float* __restrict__ qinv_,
                                                   const float* __restrict__ qoff_,
                                                   const unsigned short* __restrict__ lists2,
                                                   const unsigned char* __restrict__ lcnt2,
                                                   const unsigned long long* __restrict__ xmT,
                                                   const unsigned char* __restrict__ ak,
                                                   const unsigned char* __restrict__ av,
                                                   unsigned long long* __restrict__ msT) {
    const int tid  = threadIdx.x;
    const int lane = tid & 63;
    const int w    = tid >> 6;                   // wave 0..7
    const int nt   = blockIdx.x & 63;
    const int b    = blockIdx.x >> 6;
    const int voff = lane * 12;                  // 12B per lane: o = lane*6 + e

    float qi[6], qo[6];
    #pragma unroll
    for (int e = 0; e < 6; ++e) {
        qi[e] = qinv_[lane * 6 + e];
        qo[e] = qoff_[lane * 6 + e];
    }
    // lane-cache the block's gather metadata: lane u holds unit u's 24 u16 offsets
    const char* lb = (const char*)lists2 + (size_t)blockIdx.x * 3072 + lane * 48;
    const uint4 L0 = *(const uint4*)lb;           // slots 0-7
    const uint4 L1 = *(const uint4*)(lb + 16);    // slots 8-15
    const uint4 L2 = *(const uint4*)(lb + 32);    // slots 16-23
    const unsigned lcv = *(const unsigned*)((const char*)lcnt2
                          + (size_t)blockIdx.x * 64 + (lane & 15) * 4);

    #pragma unroll
    for (int i = 0; i < 2; ++i) {
        const int nl = w * 2 + i;                // n-local 0..15 (wave-uniform)
        const int n  = nt * 16 + nl;
        const unsigned lcw = RL(lcv, nl);        // 4 round-counts (one per t)
        f32x2 a0[4], a1[4], a2[4];
        // ---- phase 1: fixed 16 slots per t, 8-slot batches (compiler-scheduled) ----
        #pragma unroll
        for (int t = 0; t < 4; ++t) {
            const int un = nl * 4 + t;           // wave-uniform unit index
            const unsigned Wa = RL(L0.x, un), Wb = RL(L0.y, un);
            const unsigned Wc = RL(L0.z, un), Wd = RL(L0.w, un);
            const unsigned We = RL(L1.x, un), Wf = RL(L1.y, un);
            const unsigned Wg = RL(L1.z, un), Wh = RL(L1.w, un);
            f32x2 s0 = {0.f, 0.f}, s1 = {0.f, 0.f}, s2 = {0.f, 0.f};
            GROW8(Wa, Wb, Wc, Wd);
            GROW8(We, Wf, Wg, Wh);
            a0[t] = s0; a1[t] = s1; a2[t] = s2;
        }
        // ---- phase 2: rare third round (k = 17..24) ----
        #pragma unroll
        for (int t = 0; t < 4; ++t) {
            if (((lcw >> (8 * t)) & 0xffu) == 3u) {
                const int un = nl * 4 + t;
                const unsigned Wa = RL(L2.x, un), Wb = RL(L2.y, un);
                const unsigned Wc = RL(L2.z, un), Wd = RL(L2.w, un);
                f32x2 s0 = a0[t], s1 = a1[t], s2 = a2[t];
                GROW8(Wa, Wb, Wc, Wd);
                a0[t] = s0; a1[t] = s1; a2[t] = s2;
            }
        }
        // ---- phase 3: overflow fallback (k > 24, ~never), recompute from zero ----
        #pragma unroll
        for (int t = 0; t < 4; ++t) {
            if (((lcw >> (8 * t)) & 0xffu) == 0xffu) {
                const int col = ((t * 16 + b) << 10) + n;
                const unsigned long long* mp = xmT + (size_t)col * 6;
                f32x2 s0 = {0.f, 0.f}, s1 = {0.f, 0.f}, s2 = {0.f, 0.f};
                #pragma unroll
                for (int cg = 0; cg < 6; ++cg) {
                    unsigned long long mm = mp[cg];
                    while (mm) {
                        int j = __builtin_ctzll(mm);
                        mm &= mm - 1;
                        uint3 dd = *(const uint3*)(wqc + (size_t)(cg * 64 + j) * 768 + voff);
                        s0 += PK(dd.x); s1 += PK(dd.y); s2 += PK(dd.z);
                    }
                }
                a0[t] = s0; a1[t] = s1; a2[t] = s2;
            }
        }
        // ---- BN + LIF + attn-mask epilogue (6 owned o's per lane) ----
        float v[6] = {0.f, 0.f, 0.f, 0.f, 0.f, 0.f};
        #pragma unroll
        for (int t = 0; t < 4; ++t) {
            const int col = ((t * 16 + b) << 10) + n;
            const float val[6] = {a0[t].x, a0[t].y, a1[t].x, a1[t].y, a2[t].x, a2[t].y};
            bool sp[6];
            #pragma unroll
            for (int e = 0; e < 6; ++e) {
                float q = val[e] * qi[e] + qo[e];
                float h = 0.5f * (v[e] + q);     // v + (q - v)/2
                bool s = (h >= 1.0f);
                v[e] = s ? 0.f : h;
                if (s) {                          // rare: attn lookup only on q-spike
                    size_t ix = ((size_t)((t * 16 + b) * 384 + lane * 6 + e) << 10) + n;
                    s = (ak[ix] != 0) && (av[ix] != 0);
                }
                sp[e] = s;
            }
            unsigned long long B0 = __ballot(sp[0]);
            unsigned long long B1 = __ballot(sp[1]);
            unsigned long long B2 = __ballot(sp[2]);
            unsigned long long B3 = __ballot(sp[3]);
            unsigned long long B4 = __ballot(sp[4]);
            unsigned long long B5 = __ballot(sp[5]);
            // word e: bit l -> o = l*6 + e
            unsigned long long sel = lane == 0 ? B0 : lane == 1 ? B1 : lane == 2 ? B2
                                   : lane == 3 ? B3 : lane == 4 ? B4 : B5;
            if (lane < 6) msT[(size_t)col * 6 + lane] = sel;
        }
    }
}

// ---------------- K3: proj GEMM2 + bias + BN (gather-based, atomic-free) ----------
__global__ __launch_bounds__(384) void k3_proj(const float* __restrict__ wpT,
                                               const float* __restrict__ pinv_,
                                               const float* __restrict__ poff_,
                                               const float* __restrict__ bp,
                                               const float* __restrict__ c0,
                                               const unsigned long long* __restrict__ msT,
                                               float* __restrict__ out) {
    __shared__ unsigned int wflag[6];
    const int tid = threadIdx.x;
    const int bid = blockIdx.x;
    const int g = bid & 15, b = (bid >> 4) & 15, t = bid >> 8;
    const unsigned long long* mbase = msT + ((size_t)(t * 16 + b) * 1024 + g * 64) * 6;
    unsigned long long m = mbase[tid];           // 384 words: n-local = tid/6, e = tid%6
    unsigned long long anyb = __ballot(m != 0ull);
    if ((tid & 63) == 0) wflag[tid >> 6] = (anyb != 0ull) ? 1u : 0u;
    __syncthreads();
    unsigned int any = wflag[0] | wflag[1] | wflag[2] | wflag[3] | wflag[4] | wflag[5];
    size_t obase = (size_t)(t * 16 + b) * 384;

    if (!any) {
        // all-zero GEMM2 input: out = bp*inv + off, coalesced float4 stores
        #pragma unroll
        for (int k = 0; k < 16; ++k) {
            int i = tid + k * 384;               // 6144 float4 units in the (384o x 64n) tile
            int o = i >> 4, n4 = i & 15;
            float vv = c0[o];
            float4* dst = (float4*)out + (obase + o) * 256 + g * 16 + n4;
            *dst = make_float4(vv, vv, vv, vv);
        }
        return;
    }
    // slow path (never taken on this input): per-n VGPR gather.
    // word e: bit j -> input channel j*6 + e   [matches k2's layout]
    float pi = pinv_[tid], po = poff_[tid], bb = bp[tid];
    for (int nl = 0; nl < 64; ++nl) {
        float acc = 0.f;
        #pragma unroll
        for (int u = 0; u < 6; ++u) {
            unsigned long long mm = mbase[nl * 6 + u];
            while (mm) {
                int j = __builtin_ctzll(mm);
                mm &= mm - 1;
                int row = j * 6 + u;
                acc += wpT[(size_t)row * 384 + tid];
            }
        }
        out[(obase + tid) * 1024 + g * 64 + nl] = (acc + bb) * pi + po;
    }
}

extern "C" void kernel_launch(void* const* d_in, const int* in_sizes, int n_in,
                              void* d_out, int out_size, void* d_ws, size_t ws_size,
                              hipStream_t stream) {
    const float* x  = (const float*)d_in[0];
    const unsigned char* ak = (const unsigned char*)d_in[1];
    const unsigned char* av = (const unsigned char*)d_in[2];
    const float* wq = (const float*)d_in[3];
    const float* qg = (const float*)d_in[4];
    const float* qb = (const float*)d_in[5];
    const float* qm = (const float*)d_in[6];
    const float* qv = (const float*)d_in[7];
    const float* wp = (const float*)d_in[8];
    const float* bp = (const float*)d_in[9];
    const float* pg = (const float*)d_in[10];
    const float* pb = (const float*)d_in[11];
    const float* pm = (const float*)d_in[12];
    const float* pv = (const float*)d_in[13];
    char* ws = (char*)d_ws;
    float* out = (float*)d_out;

    hipLaunchKernelGGL(k0_transpose, dim3(1154), dim3(256), 0, stream, wq, wp, ws);
    hipLaunchKernelGGL(k0_consts, dim3(1), dim3(384), 0, stream,
                       qg, qb, qm, qv, pg, pb, pm, pv, bp, ws);
    hipLaunchKernelGGL(k1_lif, dim3(24576), dim3(256), 0, stream,
                       x, (unsigned long long*)(ws + XM_OFF));
    hipLaunchKernelGGL(k1b_transpose, dim3(1536), dim3(256), 0, stream,
                       (const unsigned long long*)(ws + XM_OFF),
                       (unsigned long long*)(ws + XMT_OFF));
    hipLaunchKernelGGL(k1c_lists, dim3(256), dim3(256), 0, stream,
                       (const unsigned long long*)(ws + XMT_OFF),
                       (unsigned short*)(ws + LISTS2_OFF),
                       (unsigned char*)(ws + LCNT2_OFF));
    hipLaunchKernelGGL(k2_qpath, dim3(1024), dim3(512), 0, stream,
                       (const char*)(ws + WQB_OFF),
                       (const float*)(ws + QINV_OFF), (const float*)(ws + QOFF_OFF),
                       (const unsigned short*)(ws + LISTS2_OFF),
                       (const unsigned char*)(ws + LCNT2_OFF),
                       (const unsigned long long*)(ws + XMT_OFF), ak, av,
                       (unsigned long long*)(ws + MST_OFF));
    hipLaunchKernelGGL(k3_proj, dim3(1024), dim3(384), 0, stream,
                       (const float*)(ws + WPT_OFF), (const float*)(ws + PINV_OFF),
                       (const float*)(ws + POFF_OFF), bp, (const float*)(ws + C0_OFF),
                       (const unsigned long long*)(ws + MST_OFF), out);
}